// Round 9
// baseline (194.148 us; speedup 1.0000x reference)
//
#include <hip/hip_runtime.h>

#define N_NODES 100000
#define N_EDGES 1600000
#define HID 32
#define BN_EPS 1e-5f

// deg windows: 4 x 25600 nodes (covers 102400), 64 slices
#define WND  25600
#define NWD  4
#define NSD  64
#define EPSD (N_EDGES / NSD)      // 25000
// scatter windows: 10 x 10240 nodes (covers 102400), 32 slices
#define WNS  10240
#define NWS  10
#define NSS  32
#define EPSS (N_EDGES / NSS)      // 50000

// ============================ main path ============================

// pairs[e] = (dst, src); also zero stats
__global__ void pack_kernel(const int* __restrict__ src, const int* __restrict__ dst,
                            uint2* __restrict__ pairs, float* __restrict__ stats) {
    if (blockIdx.x == 0 && threadIdx.x < 16) stats[threadIdx.x] = 0.f;
    int stride = gridDim.x * blockDim.x;
    for (int e = blockIdx.x * blockDim.x + threadIdx.x; e < N_EDGES; e += stride)
        pairs[e] = make_uint2((unsigned)dst[e], (unsigned)src[e]);
}

// (window w, slice s): LDS int histogram of in-window dst; coalesced partial write
__global__ void degwin_kernel(const uint2* __restrict__ pairs, int* __restrict__ hpart) {
    __shared__ int hist[WND];          // 100 KB
    int tid = threadIdx.x;
    int w = blockIdx.x >> 6;           // / NSD
    int s = blockIdx.x & 63;           // % NSD
    for (int j = tid; j < WND; j += 1024) hist[j] = 0;
    __syncthreads();
    unsigned w0 = (unsigned)(w * WND);
    int e0 = s * EPSD, e1 = e0 + EPSD;
    for (int e = e0 + tid; e < e1; e += 1024) {
        unsigned o = pairs[e].x - w0;
        if (o < WND) atomicAdd(&hist[o], 1);
    }
    __syncthreads();
    int* dstp = hpart + (size_t)blockIdx.x * WND;
    for (int j = tid; j < WND; j += 1024) dstp[j] = hist[j];
}

// per node: deg = sum of 64 partials; xd[n] = (x*rd, rd)
__global__ void xd_kernel(const int* __restrict__ hpart, const float* __restrict__ x,
                          float4* __restrict__ xd) {
    int n = blockIdx.x * blockDim.x + threadIdx.x;
    if (n >= N_NODES) return;
    int w = n / WND, o = n - w * WND;
    const int* hp = hpart + (size_t)(w * NSD) * WND + o;
    int deg = 0;
#pragma unroll
    for (int s = 0; s < NSD; ++s) deg += hp[(size_t)s * WND];
    float rd = rsqrtf(1.0f + (float)deg);
    xd[n] = make_float4(x[3 * n] * rd, x[3 * n + 1] * rd, x[3 * n + 2] * rd, rd);
}

// (window w, slice s): gather xd[src] for in-window dst, LDS float accumulate,
// coalesced partial write. No global atomics, no scattered writes.
__global__ void scatwin_kernel(const uint2* __restrict__ pairs, const float4* __restrict__ xd,
                               float* __restrict__ spart) {
    __shared__ float S[WNS * 3];       // 120 KB
    int tid = threadIdx.x;
    int w = blockIdx.x >> 5;           // / NSS
    int s = blockIdx.x & 31;           // % NSS
    for (int j = tid; j < WNS * 3; j += 1024) S[j] = 0.f;
    __syncthreads();
    unsigned w0 = (unsigned)(w * WNS);
    int e0 = s * EPSS, e1 = e0 + EPSS;
    for (int e = e0 + tid; e < e1; e += 1024) {
        uint2 p = pairs[e];
        unsigned o = p.x - w0;
        if (o < WNS) {
            float4 v = xd[p.y];
            atomicAdd(&S[o * 3 + 0], v.x);
            atomicAdd(&S[o * 3 + 1], v.y);
            atomicAdd(&S[o * 3 + 2], v.z);
        }
    }
    __syncthreads();
    float* dstp = spart + (size_t)blockIdx.x * (WNS * 3);
    for (int j = tid; j < WNS * 3; j += 1024) dstp[j] = S[j];
}

// per node: S = self + sum of 32 partials; write S4; fused 9-scalar BN stats
__global__ void sreduce_kernel(const float* __restrict__ spart, const float4* __restrict__ xd,
                               float4* __restrict__ S4, float* __restrict__ stats) {
    __shared__ float ls[4][9];
    int tid = threadIdx.x;
    int n = blockIdx.x * blockDim.x + tid;
    float st[9];
#pragma unroll
    for (int q = 0; q < 9; ++q) st[q] = 0.f;
    if (n < N_NODES) {
        int w = n / WNS, o = n - w * WNS;
        float4 self = xd[n];
        float sx = self.x, sy = self.y, sz = self.z;
        const float* sp = spart + (size_t)(w * NSS) * (WNS * 3) + (size_t)o * 3;
#pragma unroll
        for (int s = 0; s < NSS; ++s) {
            const float* q2 = sp + (size_t)s * (WNS * 3);
            sx += q2[0]; sy += q2[1]; sz += q2[2];
        }
        S4[n] = make_float4(sx, sy, sz, self.w);
        float ax = self.w * sx, ay = self.w * sy, az = self.w * sz;
        st[0] = ax; st[1] = ay; st[2] = az;
        st[3] = ax * ax; st[4] = ax * ay; st[5] = ax * az;
        st[6] = ay * ay; st[7] = ay * az; st[8] = az * az;
    }
    for (int m = 1; m < 64; m <<= 1)
#pragma unroll
        for (int q = 0; q < 9; ++q) st[q] += __shfl_xor(st[q], m);
    int wv = tid >> 6;
    if ((tid & 63) == 0)
#pragma unroll
        for (int q = 0; q < 9; ++q) ls[wv][q] = st[q];
    __syncthreads();
    if (tid < 9) {
        float s = ls[0][tid] + ls[1][tid] + ls[2][tid] + ls[3][tid];
        atomicAdd(&stats[tid], s);
    }
}

// fused BN-fold + streaming output
__global__ void final_out_kernel(const float4* __restrict__ S4, const float* __restrict__ stats,
                                 const float* __restrict__ W, const float* __restrict__ bb,
                                 const float* __restrict__ gamma, const float* __restrict__ beta,
                                 const float* __restrict__ prelu, float* __restrict__ out) {
    __shared__ float cb[4 * HID];
    int tid = threadIdx.x;
    if (tid < HID) {
        int c = tid;
        float m1x = stats[0], m1y = stats[1], m1z = stats[2];
        float Mxx = stats[3], Mxy = stats[4], Mxz = stats[5];
        float Myy = stats[6], Myz = stats[7], Mzz = stats[8];
        float w0 = W[c], w1 = W[HID + c], w2 = W[2 * HID + c];
        const float invn = 1.0f / (float)N_NODES;
        float m1w = m1x * w0 + m1y * w1 + m1z * w2;
        float mean = m1w * invn + bb[c];
        float quad = w0 * w0 * Mxx + w1 * w1 * Myy + w2 * w2 * Mzz
                   + 2.f * (w0 * w1 * Mxy + w0 * w2 * Mxz + w1 * w2 * Myz);
        float ex2 = quad * invn + 2.f * bb[c] * m1w * invn + bb[c] * bb[c];
        float var = ex2 - mean * mean;
        float sc = gamma[c] * rsqrtf(var + BN_EPS);
        cb[c] = w0 * sc;
        cb[HID + c] = w1 * sc;
        cb[2 * HID + c] = w2 * sc;
        cb[3 * HID + c] = bb[c] * sc + (beta[c] - mean * sc);
    }
    __syncthreads();
    float a = prelu[0];
    int stride = gridDim.x * blockDim.x;
    for (int t = blockIdx.x * blockDim.x + tid; t < N_NODES * HID; t += stride) {
        int n = t >> 5, c = t & 31;
        float4 s = S4[n];
        float y = s.w * (s.x * cb[c] + s.y * cb[HID + c] + s.z * cb[2 * HID + c])
                + cb[3 * HID + c];
        out[t] = y >= 0.f ? y : a * y;
    }
}

// ============================ fallback (round-4) path ============================

__global__ void fb_count_kernel(const int* __restrict__ dst, int* __restrict__ cnt) {
    int e = blockIdx.x * blockDim.x + threadIdx.x;
    if (e < N_EDGES) atomicAdd(&cnt[dst[e]], 1);
}

__global__ void fb_xd_kernel(const float* __restrict__ x, const int* __restrict__ cnt,
                             float4* __restrict__ xd, float4* __restrict__ S4) {
    int n = blockIdx.x * blockDim.x + threadIdx.x;
    if (n >= N_NODES) return;
    float rd = rsqrtf(1.0f + (float)cnt[n]);
    float4 v = make_float4(x[3 * n] * rd, x[3 * n + 1] * rd, x[3 * n + 2] * rd, rd);
    xd[n] = v;
    S4[n] = v;
}

__global__ void fb_scatter_kernel(const int* __restrict__ src, const int* __restrict__ dst,
                                  const float4* __restrict__ xd, float4* __restrict__ S4) {
    int e = blockIdx.x * blockDim.x + threadIdx.x;
    if (e >= N_EDGES) return;
    int s = src[e], d = dst[e];
    float4 v = xd[s];
    float* p = (float*)&S4[d];
    atomicAdd(p + 0, v.x);
    atomicAdd(p + 1, v.y);
    atomicAdd(p + 2, v.z);
}

__global__ void fb_stats_kernel(const float4* __restrict__ S4, float* __restrict__ stats) {
    __shared__ float ls[4][9];
    int tid = threadIdx.x;
    int n = blockIdx.x * blockDim.x + tid;
    float st[9];
#pragma unroll
    for (int q = 0; q < 9; ++q) st[q] = 0.f;
    if (n < N_NODES) {
        float4 s = S4[n];
        float ax = s.w * s.x, ay = s.w * s.y, az = s.w * s.z;
        st[0] = ax; st[1] = ay; st[2] = az;
        st[3] = ax * ax; st[4] = ax * ay; st[5] = ax * az;
        st[6] = ay * ay; st[7] = ay * az; st[8] = az * az;
    }
    for (int m = 1; m < 64; m <<= 1)
#pragma unroll
        for (int q = 0; q < 9; ++q) st[q] += __shfl_xor(st[q], m);
    int wv = tid >> 6;
    if ((tid & 63) == 0)
#pragma unroll
        for (int q = 0; q < 9; ++q) ls[wv][q] = st[q];
    __syncthreads();
    if (tid < 9) {
        float s = ls[0][tid] + ls[1][tid] + ls[2][tid] + ls[3][tid];
        atomicAdd(&stats[tid], s);
    }
}

// ============================ launch ============================

extern "C" void kernel_launch(void* const* d_in, const int* in_sizes, int n_in,
                              void* d_out, int out_size, void* d_ws, size_t ws_size,
                              hipStream_t stream) {
    const float* x     = (const float*)d_in[0];
    const int*   ei    = (const int*)d_in[1];   // [2, E]: src row then dst row
    const float* W     = (const float*)d_in[2];
    const float* b     = (const float*)d_in[3];
    const float* gamma = (const float*)d_in[4];
    const float* beta  = (const float*)d_in[5];
    const float* prelu = (const float*)d_in[6];

    const int* src = ei;
    const int* dst = ei + N_EDGES;
    char* ws = (char*)d_ws;
    float* out = (float*)d_out;

    // ---- ws layout (main path), total 81,536,064 B ----
    // stats @ 0           float[16]                        (64)
    // pairs @ 64          uint2[1,600,000]                 (12,800,000) -> 12,800,064
    // hpart @ 12,800,064  int[NWD*NSD=256][WND=25600]      (26,214,400) -> 39,014,464
    // spart @ 39,014,464  float[NWS*NSS=320][WNS*3=30720]  (39,321,600) -> 78,336,064
    // xd    @ 78,336,064  float4[100000]                   (1,600,000)  -> 79,936,064
    // S4    @ 79,936,064  float4[100000]                   (1,600,000)  -> 81,536,064
    const size_t NEEDED = 81536064;

    if (ws_size >= NEEDED) {
        float*  stats = (float*)(ws);
        uint2*  pairs = (uint2*)(ws + 64);
        int*    hpart = (int*)(ws + 12800064);
        float*  spart = (float*)(ws + 39014464);
        float4* xd    = (float4*)(ws + 78336064);
        float4* S4    = (float4*)(ws + 79936064);

        pack_kernel<<<2048, 256, 0, stream>>>(src, dst, pairs, stats);
        degwin_kernel<<<NWD * NSD, 1024, 0, stream>>>(pairs, hpart);
        xd_kernel<<<(N_NODES + 255) / 256, 256, 0, stream>>>(hpart, x, xd);
        scatwin_kernel<<<NWS * NSS, 1024, 0, stream>>>(pairs, xd, spart);
        sreduce_kernel<<<(N_NODES + 255) / 256, 256, 0, stream>>>(spart, xd, S4, stats);
        final_out_kernel<<<2048, 256, 0, stream>>>(S4, stats, W, b, gamma, beta, prelu, out);
    } else {
        // fallback: round-4 direct-atomic path (ws need ~3.6 MB)
        int*    cnt   = (int*)(ws);
        float*  stats = (float*)(ws + 400000);
        float4* xd    = (float4*)(ws + 400640);
        float4* S4    = (float4*)(ws + 2000640);

        hipMemsetAsync(ws, 0, 400064, stream);
        fb_count_kernel<<<(N_EDGES + 255) / 256, 256, 0, stream>>>(dst, cnt);
        fb_xd_kernel<<<(N_NODES + 255) / 256, 256, 0, stream>>>(x, cnt, xd, S4);
        fb_scatter_kernel<<<(N_EDGES + 255) / 256, 256, 0, stream>>>(src, dst, xd, S4);
        fb_stats_kernel<<<(N_NODES + 255) / 256, 256, 0, stream>>>(S4, stats);
        final_out_kernel<<<2048, 256, 0, stream>>>(S4, stats, W, b, gamma, beta, prelu, out);
    }
}

// Round 10
// 192.285 us; speedup vs baseline: 1.0097x; 1.0097x over previous
//
#include <hip/hip_runtime.h>

#define N_NODES 100000
#define N_EDGES 1600000
#define HID 32
#define BN_EPS 1e-5f

#define NW    13        // windows of 8192 nodes (13*8192 = 106496 >= 100000)
#define WNS   8192
#define NSL   256       // edge slices for count/place
#define EPSL  (N_EDGES / NSL)    // 6250
#define SPW   16        // slices per window for degw/aggw (grid 13*16 = 208)
#define SRC_MASK 0x1FFFFu

// ============================ main path ============================

// slice-block: per-wave LDS hist rows over 13 windows -> cnt[s][13]; block0 zeroes stats
__global__ void count13_kernel(const int* __restrict__ dst, int* __restrict__ cnt,
                               float* __restrict__ stats) {
    __shared__ int wh[16][NW];
    int tid = threadIdx.x, s = blockIdx.x;
    if (s == 0 && tid < 16) stats[tid] = 0.f;
    if (tid < 16 * NW) wh[tid / NW][tid % NW] = 0;
    __syncthreads();
    int wave = tid >> 6;
    int e0 = s * EPSL, e1 = e0 + EPSL;
    for (int e = e0 + tid; e < e1; e += 1024)
        atomicAdd(&wh[wave][dst[e] >> 13], 1);
    __syncthreads();
    if (tid < NW) {
        int t = 0;
#pragma unroll
        for (int w = 0; w < 16; ++w) t += wh[w][tid];
        cnt[s * NW + tid] = t;
    }
}

// single small block: column scans -> soff[s][b] (global positions), wstart[b]
__global__ void scan13_kernel(const int* __restrict__ cnt, int* __restrict__ soff,
                              int* __restrict__ wstart) {
    __shared__ int tot[NW];
    int t = threadIdx.x;
    if (t < NW) {
        int run = 0;
        for (int s = 0; s < NSL; ++s) {
            soff[s * NW + t] = run;       // column-exclusive prefix
            run += cnt[s * NW + t];
        }
        tot[t] = run;
    }
    __syncthreads();
    if (t == 0) {
        int acc = 0;
        for (int b = 0; b < NW; ++b) { wstart[b] = acc; acc += tot[b]; }
        wstart[NW] = acc;                  // == N_EDGES
    }
    __syncthreads();
    if (t < NW) {
        int base = wstart[t];
        for (int s = 0; s < NSL; ++s) soff[s * NW + t] += base;
    }
}

// slice-block: write each edge once (packed u32) into its window's contiguous
// region; rank via wave-ballot, <=13 LDS cursor atomics per wave-iteration.
__global__ void place13_kernel(const int* __restrict__ src, const int* __restrict__ dst,
                               const int* __restrict__ soff, unsigned* __restrict__ ebuf) {
    __shared__ int curs[NW];
    int tid = threadIdx.x, s = blockIdx.x;
    if (tid < NW) curs[tid] = soff[s * NW + tid];
    __syncthreads();
    int lane = tid & 63;
    int e0 = s * EPSL, e1 = e0 + EPSL;
    for (int e = e0 + tid; e < e1; e += 1024) {
        int d = dst[e];
        int w = d >> 13;
        unsigned pk = ((unsigned)(d & (WNS - 1)) << 17) | (unsigned)src[e];
        int pos = 0;
#pragma unroll 1
        for (int bq = 0; bq < NW; ++bq) {
            unsigned long long m = __ballot(w == bq);
            if (w == bq) {
                int rank = __popcll(m & ((1ull << lane) - 1ull));
                int ldr = __ffsll((long long)m) - 1;
                int wbase = 0;
                if (lane == ldr) wbase = atomicAdd(&curs[bq], __popcll(m));
                wbase = __shfl(wbase, ldr);
                pos = wbase + rank;
            }
        }
        ebuf[pos] = pk;
    }
}

// (window, slice): contiguous chunk of window's edges -> 32KB LDS int hist -> partials
__global__ void degw_kernel(const unsigned* __restrict__ ebuf, const int* __restrict__ wstart,
                            int* __restrict__ hpart) {
    __shared__ int hist[WNS];
    int tid = threadIdx.x;
    int w = blockIdx.x / SPW, sl = blockIdx.x % SPW;
    for (int j = tid; j < WNS; j += 1024) hist[j] = 0;
    __syncthreads();
    int e0 = wstart[w], e1 = wstart[w + 1];
    int len = e1 - e0, chunk = (len + SPW - 1) / SPW;
    int a0 = e0 + sl * chunk;
    int a1 = a0 + chunk; if (a1 > e1) a1 = e1;
    for (int e = a0 + tid; e < a1; e += 1024)
        atomicAdd(&hist[ebuf[e] >> 17], 1);
    __syncthreads();
    int* dstp = hpart + (size_t)blockIdx.x * WNS;
    for (int j = tid; j < WNS; j += 1024) dstp[j] = hist[j];
}

// per node: deg = sum of 16 partials; xd[n] = (x*rd, rd)
__global__ void xd_kernel(const int* __restrict__ hpart, const float* __restrict__ x,
                          float4* __restrict__ xd) {
    int n = blockIdx.x * blockDim.x + threadIdx.x;
    if (n >= N_NODES) return;
    int w = n >> 13, o = n & (WNS - 1);
    const int* hp = hpart + (size_t)(w * SPW) * WNS + o;
    int deg = 0;
#pragma unroll
    for (int sl = 0; sl < SPW; ++sl) deg += hp[(size_t)sl * WNS];
    float rd = rsqrtf(1.0f + (float)deg);
    xd[n] = make_float4(x[3 * n] * rd, x[3 * n + 1] * rd, x[3 * n + 2] * rd, rd);
}

// (window, slice): contiguous edge read (each edge ONCE), xd[src] gathers (L2),
// 96KB LDS float accumulate, coalesced partial write. No global atomics.
__global__ void aggw_kernel(const unsigned* __restrict__ ebuf, const int* __restrict__ wstart,
                            const float4* __restrict__ xd, float* __restrict__ spart) {
    __shared__ float S[WNS * 3];
    int tid = threadIdx.x;
    int w = blockIdx.x / SPW, sl = blockIdx.x % SPW;
    for (int j = tid; j < WNS * 3; j += 1024) S[j] = 0.f;
    __syncthreads();
    int e0 = wstart[w], e1 = wstart[w + 1];
    int len = e1 - e0, chunk = (len + SPW - 1) / SPW;
    int a0 = e0 + sl * chunk;
    int a1 = a0 + chunk; if (a1 > e1) a1 = e1;
    for (int e = a0 + tid; e < a1; e += 1024) {
        unsigned p = ebuf[e];
        float4 v = xd[p & SRC_MASK];
        int l3 = (int)(p >> 17) * 3;
        atomicAdd(&S[l3 + 0], v.x);
        atomicAdd(&S[l3 + 1], v.y);
        atomicAdd(&S[l3 + 2], v.z);
    }
    __syncthreads();
    float* dstp = spart + (size_t)blockIdx.x * (WNS * 3);
    for (int j = tid; j < WNS * 3; j += 1024) dstp[j] = S[j];
}

// per node: S = self + sum of 16 partials; write S4; fused 9-scalar BN stats
__global__ void sred_kernel(const float* __restrict__ spart, const float4* __restrict__ xd,
                            float4* __restrict__ S4, float* __restrict__ stats) {
    __shared__ float ls[4][9];
    int tid = threadIdx.x;
    int n = blockIdx.x * blockDim.x + tid;
    float st[9];
#pragma unroll
    for (int q = 0; q < 9; ++q) st[q] = 0.f;
    if (n < N_NODES) {
        int w = n >> 13, o = n & (WNS - 1);
        float4 self = xd[n];
        float sx = self.x, sy = self.y, sz = self.z;
        const float* sp = spart + (size_t)(w * SPW) * (WNS * 3) + (size_t)o * 3;
#pragma unroll
        for (int sl = 0; sl < SPW; ++sl) {
            const float* q2 = sp + (size_t)sl * (WNS * 3);
            sx += q2[0]; sy += q2[1]; sz += q2[2];
        }
        S4[n] = make_float4(sx, sy, sz, self.w);
        float ax = self.w * sx, ay = self.w * sy, az = self.w * sz;
        st[0] = ax; st[1] = ay; st[2] = az;
        st[3] = ax * ax; st[4] = ax * ay; st[5] = ax * az;
        st[6] = ay * ay; st[7] = ay * az; st[8] = az * az;
    }
    for (int m = 1; m < 64; m <<= 1)
#pragma unroll
        for (int q = 0; q < 9; ++q) st[q] += __shfl_xor(st[q], m);
    int wv = tid >> 6;
    if ((tid & 63) == 0)
#pragma unroll
        for (int q = 0; q < 9; ++q) ls[wv][q] = st[q];
    __syncthreads();
    if (tid < 9) {
        float s = ls[0][tid] + ls[1][tid] + ls[2][tid] + ls[3][tid];
        atomicAdd(&stats[tid], s);
    }
}

// fused BN-fold + streaming output
__global__ void final_out_kernel(const float4* __restrict__ S4, const float* __restrict__ stats,
                                 const float* __restrict__ W, const float* __restrict__ bb,
                                 const float* __restrict__ gamma, const float* __restrict__ beta,
                                 const float* __restrict__ prelu, float* __restrict__ out) {
    __shared__ float cb[4 * HID];
    int tid = threadIdx.x;
    if (tid < HID) {
        int c = tid;
        float m1x = stats[0], m1y = stats[1], m1z = stats[2];
        float Mxx = stats[3], Mxy = stats[4], Mxz = stats[5];
        float Myy = stats[6], Myz = stats[7], Mzz = stats[8];
        float w0 = W[c], w1 = W[HID + c], w2 = W[2 * HID + c];
        const float invn = 1.0f / (float)N_NODES;
        float m1w = m1x * w0 + m1y * w1 + m1z * w2;
        float mean = m1w * invn + bb[c];
        float quad = w0 * w0 * Mxx + w1 * w1 * Myy + w2 * w2 * Mzz
                   + 2.f * (w0 * w1 * Mxy + w0 * w2 * Mxz + w1 * w2 * Myz);
        float ex2 = quad * invn + 2.f * bb[c] * m1w * invn + bb[c] * bb[c];
        float var = ex2 - mean * mean;
        float sc = gamma[c] * rsqrtf(var + BN_EPS);
        cb[c] = w0 * sc;
        cb[HID + c] = w1 * sc;
        cb[2 * HID + c] = w2 * sc;
        cb[3 * HID + c] = bb[c] * sc + (beta[c] - mean * sc);
    }
    __syncthreads();
    float a = prelu[0];
    int stride = gridDim.x * blockDim.x;
    for (int t = blockIdx.x * blockDim.x + tid; t < N_NODES * HID; t += stride) {
        int n = t >> 5, c = t & 31;
        float4 s = S4[n];
        float y = s.w * (s.x * cb[c] + s.y * cb[HID + c] + s.z * cb[2 * HID + c])
                + cb[3 * HID + c];
        out[t] = y >= 0.f ? y : a * y;
    }
}

// ============================ fallback (round-4) path ============================

__global__ void fb_count_kernel(const int* __restrict__ dst, int* __restrict__ cnt) {
    int e = blockIdx.x * blockDim.x + threadIdx.x;
    if (e < N_EDGES) atomicAdd(&cnt[dst[e]], 1);
}

__global__ void fb_xd_kernel(const float* __restrict__ x, const int* __restrict__ cnt,
                             float4* __restrict__ xd, float4* __restrict__ S4) {
    int n = blockIdx.x * blockDim.x + threadIdx.x;
    if (n >= N_NODES) return;
    float rd = rsqrtf(1.0f + (float)cnt[n]);
    float4 v = make_float4(x[3 * n] * rd, x[3 * n + 1] * rd, x[3 * n + 2] * rd, rd);
    xd[n] = v;
    S4[n] = v;
}

__global__ void fb_scatter_kernel(const int* __restrict__ src, const int* __restrict__ dst,
                                  const float4* __restrict__ xd, float4* __restrict__ S4) {
    int e = blockIdx.x * blockDim.x + threadIdx.x;
    if (e >= N_EDGES) return;
    int s = src[e], d = dst[e];
    float4 v = xd[s];
    float* p = (float*)&S4[d];
    atomicAdd(p + 0, v.x);
    atomicAdd(p + 1, v.y);
    atomicAdd(p + 2, v.z);
}

__global__ void fb_stats_kernel(const float4* __restrict__ S4, float* __restrict__ stats) {
    __shared__ float ls[4][9];
    int tid = threadIdx.x;
    int n = blockIdx.x * blockDim.x + tid;
    float st[9];
#pragma unroll
    for (int q = 0; q < 9; ++q) st[q] = 0.f;
    if (n < N_NODES) {
        float4 s = S4[n];
        float ax = s.w * s.x, ay = s.w * s.y, az = s.w * s.z;
        st[0] = ax; st[1] = ay; st[2] = az;
        st[3] = ax * ax; st[4] = ax * ay; st[5] = ax * az;
        st[6] = ay * ay; st[7] = ay * az; st[8] = az * az;
    }
    for (int m = 1; m < 64; m <<= 1)
#pragma unroll
        for (int q = 0; q < 9; ++q) st[q] += __shfl_xor(st[q], m);
    int wv = tid >> 6;
    if ((tid & 63) == 0)
#pragma unroll
        for (int q = 0; q < 9; ++q) ls[wv][q] = st[q];
    __syncthreads();
    if (tid < 9) {
        float s = ls[0][tid] + ls[1][tid] + ls[2][tid] + ls[3][tid];
        atomicAdd(&stats[tid], s);
    }
}

// ============================ launch ============================

extern "C" void kernel_launch(void* const* d_in, const int* in_sizes, int n_in,
                              void* d_out, int out_size, void* d_ws, size_t ws_size,
                              hipStream_t stream) {
    const float* x     = (const float*)d_in[0];
    const int*   ei    = (const int*)d_in[1];   // [2, E]: src row then dst row
    const float* W     = (const float*)d_in[2];
    const float* b     = (const float*)d_in[3];
    const float* gamma = (const float*)d_in[4];
    const float* beta  = (const float*)d_in[5];
    const float* prelu = (const float*)d_in[6];

    const int* src = ei;
    const int* dst = ei + N_EDGES;
    char* ws = (char*)d_ws;
    float* out = (float*)d_out;

    // ---- ws layout (main path), total 36,889,728 B ----
    // stats  @ 0           float[16]                 (64)
    // wstart @ 64          int[14]                   (56) -> pad 128
    // cnt    @ 128         int[NSL*NW=3328]          (13,312) -> 13,440
    // soff   @ 13,440      int[NSL*NW]               (13,312) -> 26,752
    // ebuf   @ 26,752      u32[N_EDGES]              (6,400,000) -> 6,426,752
    // hpart  @ 6,426,752   int[208*WNS]              (6,815,744) -> 13,242,496
    // spart  @ 13,242,496  float[208*WNS*3]          (20,447,232) -> 33,689,728
    // xd     @ 33,689,728  float4[100000]            (1,600,000) -> 35,289,728
    // S4     @ 35,289,728  float4[100000]            (1,600,000) -> 36,889,728
    const size_t NEEDED = 36889728;

    if (ws_size >= NEEDED) {
        float*    stats  = (float*)(ws);
        int*      wstart = (int*)(ws + 64);
        int*      cnt    = (int*)(ws + 128);
        int*      soff   = (int*)(ws + 13440);
        unsigned* ebuf   = (unsigned*)(ws + 26752);
        int*      hpart  = (int*)(ws + 6426752);
        float*    spart  = (float*)(ws + 13242496);
        float4*   xd     = (float4*)(ws + 33689728);
        float4*   S4     = (float4*)(ws + 35289728);

        count13_kernel<<<NSL, 1024, 0, stream>>>(dst, cnt, stats);
        scan13_kernel<<<1, 64, 0, stream>>>(cnt, soff, wstart);
        place13_kernel<<<NSL, 1024, 0, stream>>>(src, dst, soff, ebuf);
        degw_kernel<<<NW * SPW, 1024, 0, stream>>>(ebuf, wstart, hpart);
        xd_kernel<<<(N_NODES + 255) / 256, 256, 0, stream>>>(hpart, x, xd);
        aggw_kernel<<<NW * SPW, 1024, 0, stream>>>(ebuf, wstart, xd, spart);
        sred_kernel<<<(N_NODES + 255) / 256, 256, 0, stream>>>(spart, xd, S4, stats);
        final_out_kernel<<<2048, 256, 0, stream>>>(S4, stats, W, b, gamma, beta, prelu, out);
    } else {
        // fallback: round-4 direct-atomic path (ws need ~3.6 MB)
        int*    cnt   = (int*)(ws);
        float*  stats = (float*)(ws + 400000);
        float4* xd    = (float4*)(ws + 400640);
        float4* S4    = (float4*)(ws + 2000640);

        hipMemsetAsync(ws, 0, 400064, stream);
        fb_count_kernel<<<(N_EDGES + 255) / 256, 256, 0, stream>>>(dst, cnt);
        fb_xd_kernel<<<(N_NODES + 255) / 256, 256, 0, stream>>>(x, cnt, xd, S4);
        fb_scatter_kernel<<<(N_EDGES + 255) / 256, 256, 0, stream>>>(src, dst, xd, S4);
        fb_stats_kernel<<<(N_NODES + 255) / 256, 256, 0, stream>>>(S4, stats);
        final_out_kernel<<<2048, 256, 0, stream>>>(S4, stats, W, b, gamma, beta, prelu, out);
    }
}